// Round 6
// baseline (211.058 us; speedup 1.0000x reference)
//
#include <hip/hip_runtime.h>
#include <math.h>

#define NANCH 896
#define MAXD 64
#define NS 14   // 896 / 64 slots per lane

__device__ __forceinline__ float selv17(const float d[17], int c) {
    float v = d[0];
#pragma unroll
    for (int k = 1; k < 17; ++k) v = (c == k) ? d[k] : v;
    return v;
}

// One WAVE per batch, 4 independent waves/block, no LDS, no barriers.
// Minimal live state (rem[14] only) -> no VGPR->LDS spill; box coords are
// re-decoded from the L1-hot anchors table + raw row on demand.
__global__ __launch_bounds__(256, 2) void blaze_wave_kernel(
    const float* __restrict__ raw_boxes,   // [B,896,16]
    const float* __restrict__ raw_scores,  // [B,896]
    const float* __restrict__ anchors,     // [896,4]
    const float* __restrict__ tmat,        // [B,8]
    const int* __restrict__ hptr,
    const int* __restrict__ wptr,
    float* __restrict__ out,               // [B,64,17]
    int B)
{
    const int lane = threadIdx.x & 63;
    const int wv   = threadIdx.x >> 6;
    const int b    = blockIdx.x * 4 + wv;
    if (b >= B) return;

    const float* rb = raw_boxes  + (size_t)b * (NANCH * 16);
    const float* rs = raw_scores + (size_t)b * NANCH;
    const float inv = 1.f / 128.f;

    // ---- scores: 14 independent coalesced loads, then sigmoid ----
    float xv[NS];
#pragma unroll
    for (int j = 0; j < NS; ++j) xv[j] = rs[lane + 64 * j];

    float rem[NS];
#pragma unroll
    for (int j = 0; j < NS; ++j) {
        float x = fminf(fmaxf(xv[j], -100.f), 100.f);
        float s = 1.f / (1.f + expf(-x));   // only x>=0 side consumed
        rem[j] = (s >= 0.5f) ? s : -1.f;
    }

    const float* M = tmat + (size_t)b * 8;
    const float m0 = M[0], m1 = M[1], m3 = M[3];
    const float m4 = M[4], m5 = M[5], m7 = M[7];
    const float hf = (float)(*hptr);
    const float wf = (float)(*wptr);
    float* ob = out + (size_t)b * (MAXD * 17);

    int iter = 0;
    while (true) {
        // ---- argmax(rem), first-index tie-break ----
        float bv = -2.f; int bi = 1 << 30;
#pragma unroll
        for (int j = 0; j < NS; ++j) {
            if (rem[j] > bv) { bv = rem[j]; bi = lane + 64 * j; }
        }
#pragma unroll
        for (int s2 = 32; s2 >= 1; s2 >>= 1) {
            float ov = __shfl_xor(bv, s2, 64);
            int   oi = __shfl_xor(bi, s2, 64);
            if (ov > bv || (ov == bv && oi < bi)) { bv = ov; bi = oi; }
        }

        if (bv <= 0.f) {
            int n = (MAXD - iter) * 17;
            float* op = ob + iter * 17;
            for (int e = lane; e < n; e += 64) op[e] = 0.f;
            break;
        }

        // ---- best box: decode from its (single, wave-uniform) line ----
        float bby0, bbx0, bby1, bbx1;
        {
            float4 an = *(const float4*)(anchors + bi * 4);
            float4 r0 = *(const float4*)(rb + bi * 16);
            float xc = r0.x * inv * an.z + an.x;
            float yc = r0.y * inv * an.w + an.y;
            float ww = r0.z * inv * an.z;
            float hh = r0.w * inv * an.w;
            bby0 = yc - hh * 0.5f; bbx0 = xc - ww * 0.5f;
            bby1 = yc + hh * 0.5f; bbx1 = xc + ww * 0.5f;
        }
        const float a1 = fmaxf(bby1 - bby0, 0.f) * fmaxf(bbx1 - bbx0, 0.f);

        float acc[16];
#pragma unroll
        for (int c = 0; c < 16; ++c) acc[c] = 0.f;
        float wsum = 0.f;
        bool anyov = false;

#pragma unroll
        for (int j = 0; j < NS; ++j) {
            if (rem[j] > 0.f) {
                const int a = lane + 64 * j;
                float4 an = *(const float4*)(anchors + a * 4);   // L1-hot table
                float4 r0 = *(const float4*)(rb + a * 16);       // cold once, then L1
                float xc = r0.x * inv * an.z + an.x;
                float yc = r0.y * inv * an.w + an.y;
                float ww = r0.z * inv * an.z;
                float hh = r0.w * inv * an.w;
                float c0 = yc - hh * 0.5f, c1 = xc - ww * 0.5f;
                float c2 = yc + hh * 0.5f, c3 = xc + ww * 0.5f;
                float ai = fmaxf(c2 - c0, 0.f) * fmaxf(c3 - c1, 0.f);
                float yA = fmaxf(bby0, c0);
                float xA = fmaxf(bbx0, c1);
                float yB = fminf(bby1, c2);
                float xB = fminf(bbx1, c3);
                float inter = fmaxf(yB - yA, 0.f) * fmaxf(xB - xA, 0.f);
                float iou = inter / fmaxf(a1 + ai - inter, 1e-6f);
                if (iou > 0.3f) {
                    anyov = true;
                    float wj = rem[j];          // rem>0 ==> rem == score
                    rem[j] = -1.f;
                    wsum += wj;
                    acc[0] += c0 * wj; acc[1] += c1 * wj;
                    acc[2] += c2 * wj; acc[3] += c3 * wj;
                    const float* rp = rb + a * 16;
                    float4 r1 = *(const float4*)(rp + 4);
                    float4 r2 = *(const float4*)(rp + 8);
                    float4 r3 = *(const float4*)(rp + 12);
                    acc[4]  += (r1.x * inv * an.z + an.x) * wj;
                    acc[5]  += (r1.y * inv * an.w + an.y) * wj;
                    acc[6]  += (r1.z * inv * an.z + an.x) * wj;
                    acc[7]  += (r1.w * inv * an.w + an.y) * wj;
                    acc[8]  += (r2.x * inv * an.z + an.x) * wj;
                    acc[9]  += (r2.y * inv * an.w + an.y) * wj;
                    acc[10] += (r2.z * inv * an.z + an.x) * wj;
                    acc[11] += (r2.w * inv * an.w + an.y) * wj;
                    acc[12] += (r3.x * inv * an.z + an.x) * wj;
                    acc[13] += (r3.y * inv * an.w + an.y) * wj;
                    acc[14] += (r3.z * inv * an.z + an.x) * wj;
                    acc[15] += (r3.w * inv * an.w + an.y) * wj;
                }
            }
        }

        bool stuck = (__ballot(anyov) == 0ull);  // nothing removed -> fixed point

        float det[17];
        if (!stuck) {
#pragma unroll
            for (int s2 = 32; s2 >= 1; s2 >>= 1) {
                wsum += __shfl_xor(wsum, s2, 64);
#pragma unroll
                for (int c = 0; c < 16; ++c) acc[c] += __shfl_xor(acc[c], s2, 64);
            }
            float dnm = fmaxf(wsum, 1e-6f);
#pragma unroll
            for (int c = 0; c < 16; ++c) det[c] = acc[c] / dnm;
        } else {
#pragma unroll
            for (int c = 0; c < 16; ++c) det[c] = 0.f;
        }
        det[16] = bv;

        // ---- project + rescale ----
        {
            const int xi[8] = { 1, 3, 4, 6, 8, 10, 12, 14 };
            const int yi[8] = { 0, 2, 5, 7, 9, 11, 13, 15 };
#pragma unroll
            for (int k = 0; k < 8; ++k) {
                float x = det[xi[k]], y = det[yi[k]];
                det[xi[k]] = (x * m0 + y * m1 + m3) * wf;
                det[yi[k]] = (x * m4 + y * m5 + m7) * hf;
            }
        }

        if (stuck) {
            // det is wave-uniform (post-reduction) — fill remaining rows
            int n = (MAXD - iter) * 17;
            float* op = ob + iter * 17;
            for (int e = lane; e < n; e += 64) op[e] = selv17(det, e % 17);
            break;
        } else {
            if (lane < 17) ob[iter * 17 + lane] = selv17(det, lane);
            ++iter;
            if (iter == MAXD) break;
        }
    }
}

extern "C" void kernel_launch(void* const* d_in, const int* in_sizes, int n_in,
                              void* d_out, int out_size, void* d_ws, size_t ws_size,
                              hipStream_t stream) {
    (void)n_in; (void)out_size; (void)d_ws; (void)ws_size;
    const float* raw_boxes  = (const float*)d_in[0];
    const float* raw_scores = (const float*)d_in[1];
    const float* anchors    = (const float*)d_in[2];
    const float* tmat       = (const float*)d_in[3];
    const int*   hptr       = (const int*)d_in[4];
    const int*   wptr       = (const int*)d_in[5];
    float* out = (float*)d_out;

    const int B = in_sizes[0] / (NANCH * 16);
    blaze_wave_kernel<<<(B + 3) / 4, 256, 0, stream>>>(raw_boxes, raw_scores, anchors,
                                                       tmat, hptr, wptr, out, B);
}

// Round 7
// 201.328 us; speedup vs baseline: 1.0483x; 1.0483x over previous
//
#include <hip/hip_runtime.h>
#include <math.h>

#define NANCH 896
#define MAXD 64
#define NS 14   // 896 / 64 slots per lane

__device__ __forceinline__ float selv17(const float d[17], int c) {
    float v = d[0];
#pragma unroll
    for (int k = 1; k < 17; ++k) v = (c == k) ? d[k] : v;
    return v;
}

// One WAVE per batch, 4 independent waves/block, no LDS, no barriers.
// All global loads are issued in batches BEFORE any use (issue-once,
// wait-once) to pay memory latency + queue delay once, not per-slot.
__global__ __launch_bounds__(256, 2) void blaze_wave_kernel(
    const float* __restrict__ raw_boxes,   // [B,896,16]
    const float* __restrict__ raw_scores,  // [B,896]
    const float* __restrict__ anchors,     // [896,4]
    const float* __restrict__ tmat,        // [B,8]
    const int* __restrict__ hptr,
    const int* __restrict__ wptr,
    float* __restrict__ out,               // [B,64,17]
    int B)
{
    const int lane = threadIdx.x & 63;
    const int wv   = threadIdx.x >> 6;
    const int b    = blockIdx.x * 4 + wv;
    if (b >= B) return;

    const float* rb = raw_boxes  + (size_t)b * (NANCH * 16);
    const float* rs = raw_scores + (size_t)b * NANCH;
    const float inv = 1.f / 128.f;

    // ---- Phase 1: ALL score loads issued back-to-back (14 outstanding) ----
    float xv[NS];
#pragma unroll
    for (int j = 0; j < NS; ++j) xv[j] = rs[lane + 64 * j];

    float rem[NS];
    bool  act[NS];
#pragma unroll
    for (int j = 0; j < NS; ++j) {
        float x = fminf(fmaxf(xv[j], -100.f), 100.f);
        float s = 1.f / (1.f + expf(-x));   // only x>=0 side consumed
        act[j] = (s >= 0.5f);
        rem[j] = act[j] ? s : -1.f;
    }

    // ---- Phase 2: batched r0 + anchor loads, clamped addresses (no exec gating,
    //      no extra traffic: inactive lanes alias row 0's line) ----
    float4 r0v[NS], anv[NS];
#pragma unroll
    for (int j = 0; j < NS; ++j) {
        const int a2 = act[j] ? (lane + 64 * j) : 0;
        r0v[j] = *(const float4*)(rb + a2 * 16);
        anv[j] = *(const float4*)(anchors + a2 * 4);
    }

    // ---- decode boxes for all slots unconditionally (rem gates use) ----
    float b0[NS], b1[NS], b2[NS], b3[NS];
#pragma unroll
    for (int j = 0; j < NS; ++j) {
        float xc = r0v[j].x * inv * anv[j].z + anv[j].x;
        float yc = r0v[j].y * inv * anv[j].w + anv[j].y;
        float ww = r0v[j].z * inv * anv[j].z;
        float hh = r0v[j].w * inv * anv[j].w;
        b0[j] = yc - hh * 0.5f; b1[j] = xc - ww * 0.5f;
        b2[j] = yc + hh * 0.5f; b3[j] = xc + ww * 0.5f;
    }

    const float* M = tmat + (size_t)b * 8;
    const float m0 = M[0], m1 = M[1], m3 = M[3];
    const float m4 = M[4], m5 = M[5], m7 = M[7];
    const float hf = (float)(*hptr);
    const float wf = (float)(*wptr);
    float* ob = out + (size_t)b * (MAXD * 17);

    int iter = 0;
    while (true) {
        // ---- argmax(rem), first-index tie-break ----
        float bv = -2.f; int bi = 1 << 30;
#pragma unroll
        for (int j = 0; j < NS; ++j) {
            if (rem[j] > bv) { bv = rem[j]; bi = lane + 64 * j; }
        }
#pragma unroll
        for (int s2 = 32; s2 >= 1; s2 >>= 1) {
            float ov = __shfl_xor(bv, s2, 64);
            int   oi = __shfl_xor(bi, s2, 64);
            if (ov > bv || (ov == bv && oi < bi)) { bv = ov; bi = oi; }
        }

        if (bv <= 0.f) {
            int n = (MAXD - iter) * 17;
            float* op = ob + iter * 17;
            for (int e = lane; e < n; e += 64) op[e] = 0.f;
            break;
        }

        // ---- broadcast best box from owning lane/slot (registers only) ----
        const int bl = bi & 63, bj = bi >> 6;
        float vb0 = b0[0], vb1 = b1[0], vb2 = b2[0], vb3 = b3[0];
#pragma unroll
        for (int j = 1; j < NS; ++j) {
            if (bj == j) { vb0 = b0[j]; vb1 = b1[j]; vb2 = b2[j]; vb3 = b3[j]; }
        }
        const float bby0 = __shfl(vb0, bl, 64);
        const float bbx0 = __shfl(vb1, bl, 64);
        const float bby1 = __shfl(vb2, bl, 64);
        const float bbx1 = __shfl(vb3, bl, 64);
        const float a1 = fmaxf(bby1 - bby0, 0.f) * fmaxf(bbx1 - bbx0, 0.f);

        float acc[16];
#pragma unroll
        for (int c = 0; c < 16; ++c) acc[c] = 0.f;
        float wsum = 0.f;
        bool anyov = false;

#pragma unroll
        for (int j = 0; j < NS; ++j) {
            if (rem[j] > 0.f) {
                float ai = fmaxf(b2[j] - b0[j], 0.f) * fmaxf(b3[j] - b1[j], 0.f);
                float yA = fmaxf(bby0, b0[j]);
                float xA = fmaxf(bbx0, b1[j]);
                float yB = fminf(bby1, b2[j]);
                float xB = fminf(bbx1, b3[j]);
                float inter = fmaxf(yB - yA, 0.f) * fmaxf(xB - xA, 0.f);
                float iou = inter / fmaxf(a1 + ai - inter, 1e-6f);
                if (iou > 0.3f) {
                    anyov = true;
                    float wj = rem[j];          // rem>0 ==> rem == score
                    rem[j] = -1.f;
                    wsum += wj;
                    acc[0] += b0[j] * wj; acc[1] += b1[j] * wj;
                    acc[2] += b2[j] * wj; acc[3] += b3[j] * wj;
                    // keypoints refetched only for overlapped boxes (rare, hot line)
                    const int a = lane + 64 * j;
                    float4 an = *(const float4*)(anchors + a * 4);
                    const float* rp = rb + a * 16;
                    float4 r1 = *(const float4*)(rp + 4);
                    float4 r2 = *(const float4*)(rp + 8);
                    float4 r3 = *(const float4*)(rp + 12);
                    acc[4]  += (r1.x * inv * an.z + an.x) * wj;
                    acc[5]  += (r1.y * inv * an.w + an.y) * wj;
                    acc[6]  += (r1.z * inv * an.z + an.x) * wj;
                    acc[7]  += (r1.w * inv * an.w + an.y) * wj;
                    acc[8]  += (r2.x * inv * an.z + an.x) * wj;
                    acc[9]  += (r2.y * inv * an.w + an.y) * wj;
                    acc[10] += (r2.z * inv * an.z + an.x) * wj;
                    acc[11] += (r2.w * inv * an.w + an.y) * wj;
                    acc[12] += (r3.x * inv * an.z + an.x) * wj;
                    acc[13] += (r3.y * inv * an.w + an.y) * wj;
                    acc[14] += (r3.z * inv * an.z + an.x) * wj;
                    acc[15] += (r3.w * inv * an.w + an.y) * wj;
                }
            }
        }

        bool stuck = (__ballot(anyov) == 0ull);  // nothing removed -> fixed point

        float det[17];
        if (!stuck) {
#pragma unroll
            for (int s2 = 32; s2 >= 1; s2 >>= 1) {
                wsum += __shfl_xor(wsum, s2, 64);
#pragma unroll
                for (int c = 0; c < 16; ++c) acc[c] += __shfl_xor(acc[c], s2, 64);
            }
            float dnm = fmaxf(wsum, 1e-6f);
#pragma unroll
            for (int c = 0; c < 16; ++c) det[c] = acc[c] / dnm;
        } else {
#pragma unroll
            for (int c = 0; c < 16; ++c) det[c] = 0.f;
        }
        det[16] = bv;

        // ---- project + rescale ----
        {
            const int xi[8] = { 1, 3, 4, 6, 8, 10, 12, 14 };
            const int yi[8] = { 0, 2, 5, 7, 9, 11, 13, 15 };
#pragma unroll
            for (int k = 0; k < 8; ++k) {
                float x = det[xi[k]], y = det[yi[k]];
                det[xi[k]] = (x * m0 + y * m1 + m3) * wf;
                det[yi[k]] = (x * m4 + y * m5 + m7) * hf;
            }
        }

        if (stuck) {
            // det is wave-uniform (post-reduction) — fill remaining rows
            int n = (MAXD - iter) * 17;
            float* op = ob + iter * 17;
            for (int e = lane; e < n; e += 64) op[e] = selv17(det, e % 17);
            break;
        } else {
            if (lane < 17) ob[iter * 17 + lane] = selv17(det, lane);
            ++iter;
            if (iter == MAXD) break;
        }
    }
}

extern "C" void kernel_launch(void* const* d_in, const int* in_sizes, int n_in,
                              void* d_out, int out_size, void* d_ws, size_t ws_size,
                              hipStream_t stream) {
    (void)n_in; (void)out_size; (void)d_ws; (void)ws_size;
    const float* raw_boxes  = (const float*)d_in[0];
    const float* raw_scores = (const float*)d_in[1];
    const float* anchors    = (const float*)d_in[2];
    const float* tmat       = (const float*)d_in[3];
    const int*   hptr       = (const int*)d_in[4];
    const int*   wptr       = (const int*)d_in[5];
    float* out = (float*)d_out;

    const int B = in_sizes[0] / (NANCH * 16);
    blaze_wave_kernel<<<(B + 3) / 4, 256, 0, stream>>>(raw_boxes, raw_scores, anchors,
                                                       tmat, hptr, wptr, out, B);
}